// Round 9
// baseline (158.611 us; speedup 1.0000x reference)
//
#include <hip/hip_runtime.h>
#include <hip/hip_bf16.h>

typedef __attribute__((ext_vector_type(8))) short short8;
typedef __attribute__((ext_vector_type(4))) float floatx4;

#define MARGIN 0.3f
static constexpr int N = 8192;   // b*n points
static constexpr int C = 256;    // feature dim

// ---------------- kernel 0: fp32->bf16 convert + row norms + init --------------
// blocks [0, N/4): one wave per row (4 rows / 256-thr block)
// blocks [N/4, N/4+64): fused mse + dr partial reductions -> scalars[1+b]
__global__ void k_prep_sq(const float* __restrict__ feat, __hip_bfloat16* __restrict__ fb,
                          float* __restrict__ sq, unsigned* __restrict__ posmax,
                          unsigned* __restrict__ negmin,
                          const float* __restrict__ s0, const float* __restrict__ s1,
                          const float* __restrict__ s2, const float* __restrict__ gt,
                          const float* __restrict__ e0, const float* __restrict__ e1,
                          const float* __restrict__ l0, const float* __restrict__ l1,
                          float* __restrict__ scalars) {
    if (blockIdx.x >= N / 4) {
        const int E = 64 * 1024;
        int bid = blockIdx.x - N / 4;
        int tid = bid * 256 + threadIdx.x;
        int nth = 64 * 256;
        float acc = 0.f;
        for (int i = tid; i < E; i += nth) acc += fabsf(e0[i] - l0[i]) * (1.f / E);
        for (int i = tid; i < E; i += nth) acc += fabsf(e1[i] - l1[i]) * (1.f / E);
        if (tid < 192) {
            int k = tid >> 6, i = tid & 63;
            const float* s = (k == 0) ? s0 : ((k == 1) ? s1 : s2);
            float d = s[i] - gt[i];
            acc += d * d * (1.f / 192.f);
        }
#pragma unroll
        for (int off = 32; off; off >>= 1) acc += __shfl_xor(acc, off);
        __shared__ float red[4];
        int lane = threadIdx.x & 63, wv = threadIdx.x >> 6;
        if (lane == 0) red[wv] = acc;
        __syncthreads();
        if (threadIdx.x == 0)
            scalars[1 + bid] = red[0] + red[1] + red[2] + red[3];
        return;
    }
    int row = blockIdx.x * 4 + (threadIdx.x >> 6);
    int lane = threadIdx.x & 63;
    float4 v = ((const float4*)feat)[row * 64 + lane];
    union { __hip_bfloat16 h[4]; ushort4 u; } cv;
    cv.h[0] = __float2bfloat16(v.x); cv.h[1] = __float2bfloat16(v.y);
    cv.h[2] = __float2bfloat16(v.z); cv.h[3] = __float2bfloat16(v.w);
    ((ushort4*)fb)[row * 64 + lane] = cv.u;
    float s = v.x * v.x + v.y * v.y + v.z * v.z + v.w * v.w;
#pragma unroll
    for (int off = 32; off; off >>= 1) s += __shfl_xor(s, off);
    if (lane == 0) {
        sq[row] = s;
        posmax[row] = 0u;
        negmin[row] = 0x7f800000u;   // +inf
    }
}

// ---------------- kernel 1: pairwise mining via bf16 MFMA ----------------------
// BARRIER-FREE / LDS-FREE: fb (4 MB) fits an XCD's L2, so LDS staging was pure
// overhead (Common-mistake #7) -- its only payoff (2x L2-traffic reduction,
// ~15us aggregate) cost the barrier/drain convoy that pinned k_trip at ~55us.
// Each wave now loads its B fragments (identical col/k mapping as before)
// directly global->reg and free-runs; no __syncthreads anywhere.
// Geometry unchanged: grid 64 i-tiles x 8 j-chunks, 4 waves (2x2) per block,
// A (128x256) in registers, row-side mining, atomics only at block end.
// Lesson log: b128 "bank conflicts" (2.1M = 4/read) are a PMC artifact,
// layout-invariant (R8); counted-vmcnt null on 2-phase (R8); __threadfence
// epilogue +40us (R6); min-waves=4 spills A (R4); thin phases double fixed
// cost (R5); per-phase atomics convoy (R2/R3). Do not repeat.
__global__ __launch_bounds__(256, 2)
void k_trip(const __hip_bfloat16* __restrict__ fb, const float* __restrict__ sq,
            unsigned* __restrict__ posmax, unsigned* __restrict__ negmin) {
    const int t = threadIdx.x;
    const int ib = (blockIdx.x >> 3) * 128;   // i-tile base row
    const int jc = (blockIdx.x & 7) * 1024;   // j-chunk base
    const int w = t >> 6, lane = t & 63;
    const int wi = w >> 1, wj = w & 1;
    const int quad = lane >> 4, l15 = lane & 15;

    // ---- A fragments in registers: rows wi*64 + ti*16 + l15, all K=256 ----
    short8 a[4][8];
#pragma unroll
    for (int ti = 0; ti < 4; ++ti) {
        const __hip_bfloat16* ap = fb + (size_t)(ib + wi * 64 + ti * 16 + l15) * C + quad * 8;
#pragma unroll
        for (int k = 0; k < 8; ++k)
            a[ti][k] = *(const short8*)(ap + k * 32);
    }

    // mining state: m = (sj - 2*dot); add si at the end.
    float nm[16];                 // per acc-row running min over negatives
    float pm[2];                  // positive max (this wave's diag sub-tiles)
#pragma unroll
    for (int q = 0; q < 16; ++q) nm[q] = INFINITY;
    pm[0] = -INFINITY; pm[1] = -INFINITY;

    // per-lane B base: col = jc + wj*32 + l15 (+16 for tjj=1), elem k*32+quad*8
    const __hip_bfloat16* bb = fb + (size_t)(jc + wj * 32 + l15) * C + quad * 8;

#pragma unroll 1
    for (int p = 0; p < 16; ++p) {
        const int jb = jc + p * 64;
        const __hip_bfloat16* bp0 = bb + (size_t)p * 64 * C;
        const __hip_bfloat16* bp1 = bp0 + 16 * C;

        floatx4 acc[4][2];
#pragma unroll
        for (int ti = 0; ti < 4; ++ti)
#pragma unroll
            for (int tjj = 0; tjj < 2; ++tjj)
                acc[ti][tjj] = (floatx4){0.f, 0.f, 0.f, 0.f};

        __builtin_amdgcn_s_setprio(1);
#pragma unroll
        for (int k = 0; k < 8; ++k) {
            short8 b0 = *(const short8*)(bp0 + k * 32);
            short8 b1 = *(const short8*)(bp1 + k * 32);
#pragma unroll
            for (int ti = 0; ti < 4; ++ti) {
                acc[ti][0] = __builtin_amdgcn_mfma_f32_16x16x32_bf16(a[ti][k], b0, acc[ti][0], 0, 0, 0);
                acc[ti][1] = __builtin_amdgcn_mfma_f32_16x16x32_bf16(a[ti][k], b1, acc[ti][1], 0, 0, 0);
            }
        }
        __builtin_amdgcn_s_setprio(0);

        // mining epilogue on m = sj - 2*dot
        const int jb128 = jb & ~127;          // enclosing 128-block base
        const bool par = (wi == (p & 1));     // diag band hits this wave-row?
        const bool notself = (jb128 != ib);
#pragma unroll
        for (int tjj = 0; tjj < 2; ++tjj) {
            float sj = sq[jb + wj * 32 + tjj * 16 + l15];
#pragma unroll
            for (int ti = 0; ti < 4; ++ti) {
                bool diag_tile = par && (ti == wj * 2 + tjj);
#pragma unroll
                for (int r = 0; r < 4; ++r) {
                    float v = fmaf(-2.f, acc[ti][tjj][r], sj);
                    if (diag_tile) {
                        bool isd = (l15 == quad * 4 + r);   // same label
                        nm[ti * 4 + r] = fminf(nm[ti * 4 + r], isd ? INFINITY : v);
                        if (notself)
                            pm[tjj] = fmaxf(pm[tjj], isd ? v : -INFINITY);
                    } else {
                        nm[ti * 4 + r] = fminf(nm[ti * 4 + r], v);
                    }
                }
            }
        }
    }

    // ---- final: reduce nm across the 16 lanes of each quad; owner-lane pm ----
#pragma unroll
    for (int q = 0; q < 16; ++q) {
        float v = nm[q];
#pragma unroll
        for (int off = 1; off < 16; off <<= 1) v = fminf(v, __shfl_xor(v, off));
        if (l15 == 0) {
            int row = ib + wi * 64 + (q >> 2) * 16 + quad * 4 + (q & 3);
            float d2 = fmaxf(v + sq[row], 0.f);
            atomicMin(&negmin[row], __float_as_uint(d2));
        }
    }
    if ((l15 >> 2) == quad) {     // this lane owns the tile-diag elems
#pragma unroll
        for (int s = 0; s < 2; ++s) {
            int ti = wj * 2 + s;
            int row = ib + wi * 64 + ti * 16 + l15;
            float d2 = fmaxf(pm[s] + sq[row], 0.f);
            atomicMax(&posmax[row], __float_as_uint(d2));
        }
    }
}

// ---------------- kernel 2: final combine ---------------------------------------
__global__ void k_final(const unsigned* __restrict__ posmax, const unsigned* __restrict__ negmin,
                        const float* __restrict__ scalars, float* __restrict__ out) {
    float acc = 0.f;
    for (int i = threadIdx.x; i < N; i += 1024) {
        float hp = sqrtf(__uint_as_float(posmax[i]));
        float hn = sqrtf(__uint_as_float(negmin[i]));
        acc += fmaxf(hp - hn + MARGIN, 0.f);
    }
#pragma unroll
    for (int off = 32; off; off >>= 1) acc += __shfl_xor(acc, off);
    __shared__ float red[16];
    if ((threadIdx.x & 63) == 0) red[threadIdx.x >> 6] = acc;
    __syncthreads();
    if (threadIdx.x == 0) {
        float tsum = 0.f;
#pragma unroll
        for (int i = 0; i < 16; ++i) tsum += red[i];
        float ssum = 0.f;
        for (int i = 0; i < 64; ++i) ssum += scalars[1 + i];
        out[0] = ssum + tsum * (1.f / N);
    }
}

extern "C" void kernel_launch(void* const* d_in, const int* in_sizes, int n_in,
                              void* d_out, int out_size, void* d_ws, size_t ws_size,
                              hipStream_t stream) {
    const float* feat = (const float*)d_in[0];
    const float* gt   = (const float*)d_in[1];
    const float* s0   = (const float*)d_in[2];
    const float* s1   = (const float*)d_in[3];
    const float* s2   = (const float*)d_in[4];
    const float* e0   = (const float*)d_in[5];
    const float* e1   = (const float*)d_in[6];
    const float* l0   = (const float*)d_in[7];
    const float* l1   = (const float*)d_in[8];
    float* out = (float*)d_out;

    char* ws = (char*)d_ws;
    __hip_bfloat16* fb = (__hip_bfloat16*)ws;                       // 4 MB
    float*    sq      = (float*)(ws + (size_t)N * C * 2);
    unsigned* posmax  = (unsigned*)(ws + (size_t)N * C * 2 + N * 4);
    unsigned* negmin  = (unsigned*)(ws + (size_t)N * C * 2 + N * 8);
    float*    scalars = (float*)(ws + (size_t)N * C * 2 + N * 12);  // 65 floats

    k_prep_sq<<<N / 4 + 64, 256, 0, stream>>>(feat, fb, sq, posmax, negmin,
                                              s0, s1, s2, gt, e0, e1, l0, l1, scalars);
    k_trip<<<512, 256, 0, stream>>>(fb, sq, posmax, negmin);
    k_final<<<1, 1024, 0, stream>>>(posmax, negmin, scalars, out);
}

// Round 10
// 125.417 us; speedup vs baseline: 1.2647x; 1.2647x over previous
//
#include <hip/hip_runtime.h>
#include <hip/hip_bf16.h>

typedef __attribute__((ext_vector_type(8))) short short8;
typedef __attribute__((ext_vector_type(4))) float floatx4;

#define MARGIN 0.3f
static constexpr int N = 8192;   // b*n points
static constexpr int C = 256;    // feature dim

// async 16B global->LDS (dest = wave-uniform base + lane*16)
__device__ __forceinline__ void async16(const void* g, void* l) {
    __builtin_amdgcn_global_load_lds(
        (const __attribute__((address_space(1))) unsigned int*)g,
        (__attribute__((address_space(3))) unsigned int*)l, 16, 0, 0);
}

// ---------------- kernel 0: fp32->bf16 convert + row norms + init --------------
// blocks [0, N/4): one wave per row (4 rows / 256-thr block)
// blocks [N/4, N/4+64): fused mse + dr partial reductions -> scalars[1+b]
__global__ void k_prep_sq(const float* __restrict__ feat, __hip_bfloat16* __restrict__ fb,
                          float* __restrict__ sq, unsigned* __restrict__ posmax,
                          unsigned* __restrict__ negmin,
                          const float* __restrict__ s0, const float* __restrict__ s1,
                          const float* __restrict__ s2, const float* __restrict__ gt,
                          const float* __restrict__ e0, const float* __restrict__ e1,
                          const float* __restrict__ l0, const float* __restrict__ l1,
                          float* __restrict__ scalars) {
    if (blockIdx.x >= N / 4) {
        const int E = 64 * 1024;
        int bid = blockIdx.x - N / 4;
        int tid = bid * 256 + threadIdx.x;
        int nth = 64 * 256;
        float acc = 0.f;
        for (int i = tid; i < E; i += nth) acc += fabsf(e0[i] - l0[i]) * (1.f / E);
        for (int i = tid; i < E; i += nth) acc += fabsf(e1[i] - l1[i]) * (1.f / E);
        if (tid < 192) {
            int k = tid >> 6, i = tid & 63;
            const float* s = (k == 0) ? s0 : ((k == 1) ? s1 : s2);
            float d = s[i] - gt[i];
            acc += d * d * (1.f / 192.f);
        }
#pragma unroll
        for (int off = 32; off; off >>= 1) acc += __shfl_xor(acc, off);
        __shared__ float red[4];
        int lane = threadIdx.x & 63, wv = threadIdx.x >> 6;
        if (lane == 0) red[wv] = acc;
        __syncthreads();
        if (threadIdx.x == 0)
            scalars[1 + bid] = red[0] + red[1] + red[2] + red[3];
        return;
    }
    int row = blockIdx.x * 4 + (threadIdx.x >> 6);
    int lane = threadIdx.x & 63;
    float4 v = ((const float4*)feat)[row * 64 + lane];
    union { __hip_bfloat16 h[4]; ushort4 u; } cv;
    cv.h[0] = __float2bfloat16(v.x); cv.h[1] = __float2bfloat16(v.y);
    cv.h[2] = __float2bfloat16(v.z); cv.h[3] = __float2bfloat16(v.w);
    ((ushort4*)fb)[row * 64 + lane] = cv.u;
    float s = v.x * v.x + v.y * v.y + v.z * v.z + v.w * v.w;
#pragma unroll
    for (int off = 32; off; off >>= 1) s += __shfl_xor(s, off);
    if (lane == 0) {
        sq[row] = s;
        posmax[row] = 0u;
        negmin[row] = 0x7f800000u;   // +inf
    }
}

// ---------------- kernel 1: pairwise mining via bf16 MFMA ----------------------
// ROUND-1 PROVEN OPTIMUM (54.5 us), restored, + two zero-risk micro-fixes:
//  (a) sq loads hoisted to top of COMPUTE (L2 latency hides under MFMA cluster
//      instead of stalling the pre-barrier tail);
//  (b) s_setprio removed (m190: slightly negative on barrier-locked lockstep
//      waves -- our regime).
// Grid: 64 i-tiles x 8 j-chunks. Block 256 thr = 4 waves (2x2 of 128 rows x 64
// cols). A tile (128x256) in REGISTERS. B streamed in 64-col subtiles through
// two 32 KB LDS buffers (source-XOR-swizzled), prefetch t+1 while computing t.
// Row-side mining only; atomics ONLY at block end.
// Lesson log (measured, do not repeat): per-phase atomics convoy the drain
// (R2/R3); min-waves=4 spills A -> 580 MB fetch (R4); thin 32-col phases
// double fixed per-phase cost (R5); __threadfence epilogue = per-wave L2
// writeback +40us (R6); counted-vmcnt null on 2-phase (R8); b128 "bank
// conflicts" 2.1M = 4/read PMC artifact, layout-invariant (R8); LDS-free
// direct-L2 B is latency-bound, 1.5x worse (R9).
__global__ __launch_bounds__(256, 2)
void k_trip(const __hip_bfloat16* __restrict__ fb, const float* __restrict__ sq,
            unsigned* __restrict__ posmax, unsigned* __restrict__ negmin) {
    __shared__ uint4 Bs0[2048];   // 64 cols x 32 granules (16B) = 32 KB
    __shared__ uint4 Bs1[2048];   // ping-pong partner

    const int t = threadIdx.x;
    const int ib = (blockIdx.x >> 3) * 128;   // i-tile base row
    const int jc = (blockIdx.x & 7) * 1024;   // j-chunk base
    const int w = t >> 6, lane = t & 63;
    const int wi = w >> 1, wj = w & 1;
    const int quad = lane >> 4, l15 = lane & 15;

    // ---- A fragments in registers: rows wi*64 + ti*16 + l15, all K=256 ----
    short8 a[4][8];
#pragma unroll
    for (int ti = 0; ti < 4; ++ti) {
        const __hip_bfloat16* ap = fb + (size_t)(ib + wi * 64 + ti * 16 + l15) * C + quad * 8;
#pragma unroll
        for (int k = 0; k < 8; ++k)
            a[ti][k] = *(const short8*)(ap + k * 32);
    }

    // ---- hoisted per-thread staging offsets (bf16-element units) ----
    int soff[8];
#pragma unroll
    for (int it = 0; it < 8; ++it) {
        int s = it * 256 + t;
        int srow = s >> 5, sg = s & 31;
        soff[it] = srow * C + (sg ^ (srow & 7)) * 8;
    }

    // mining state: m = (sj - 2*dot); add si at the end.
    float nm[16];                 // per acc-row running min over negatives
    float pm[2];                  // positive max (this wave's diag sub-tiles)
#pragma unroll
    for (int q = 0; q < 16; ++q) nm[q] = INFINITY;
    pm[0] = -INFINITY; pm[1] = -INFINITY;

    auto STAGE = [&](int jb, uint4* dst) {
        const __hip_bfloat16* src = fb + (size_t)jb * C;
        uint4* d = dst + (t & ~63);           // wave-uniform base
#pragma unroll
        for (int it = 0; it < 8; ++it)
            async16(src + soff[it], d + it * 256);
    };

    auto COMPUTE = [&](int jsub, const uint4* __restrict__ Br) {
        // (a) sj loads issued FIRST: ~200cy L2 latency hides under the MFMAs
        const int jb = jc + jsub * 64;
        float sj0 = sq[jb + wj * 32 + l15];
        float sj1 = sq[jb + wj * 32 + 16 + l15];

        floatx4 acc[4][2];
#pragma unroll
        for (int ti = 0; ti < 4; ++ti)
#pragma unroll
            for (int tjj = 0; tjj < 2; ++tjj)
                acc[ti][tjj] = (floatx4){0.f, 0.f, 0.f, 0.f};

#pragma unroll
        for (int k = 0; k < 8; ++k) {
            short8 b[2];
#pragma unroll
            for (int tjj = 0; tjj < 2; ++tjj) {
                int col = wj * 32 + tjj * 16 + l15;
                int g = (k * 4 + quad) ^ (col & 7);
                b[tjj] = *(const short8*)&Br[col * 32 + g];
            }
#pragma unroll
            for (int ti = 0; ti < 4; ++ti)
#pragma unroll
                for (int tjj = 0; tjj < 2; ++tjj)
                    acc[ti][tjj] = __builtin_amdgcn_mfma_f32_16x16x32_bf16(
                        a[ti][k], b[tjj], acc[ti][tjj], 0, 0, 0);
        }

        // mining epilogue on m = sj - 2*dot
        const int jb128 = jb & ~127;          // enclosing 128-block base
        const bool par = (wi == (jsub & 1));  // diag band hits this wave-row?
        const bool notself = (jb128 != ib);
#pragma unroll
        for (int tjj = 0; tjj < 2; ++tjj) {
            float sj = tjj ? sj1 : sj0;
#pragma unroll
            for (int ti = 0; ti < 4; ++ti) {
                bool diag_tile = par && (ti == wj * 2 + tjj);
#pragma unroll
                for (int r = 0; r < 4; ++r) {
                    float v = fmaf(-2.f, acc[ti][tjj][r], sj);
                    if (diag_tile) {
                        bool isd = (l15 == quad * 4 + r);   // same label
                        nm[ti * 4 + r] = fminf(nm[ti * 4 + r], isd ? INFINITY : v);
                        if (notself)
                            pm[tjj] = fmaxf(pm[tjj], isd ? v : -INFINITY);
                    } else {
                        nm[ti * 4 + r] = fminf(nm[ti * 4 + r], v);
                    }
                }
            }
        }
    };

    // ---- 2-phase pipelined main loop: stage t+1 while computing t ----
    STAGE(jc, Bs0);
    __syncthreads();
#pragma unroll 1
    for (int jp = 0; jp < 8; ++jp) {
        STAGE(jc + (jp * 2 + 1) * 64, Bs1);   // prefetch odd subtile
        COMPUTE(jp * 2, Bs0);
        __syncthreads();                       // Bs1 ready; Bs0 reads done
        if (jp < 7)
            STAGE(jc + (jp * 2 + 2) * 64, Bs0); // prefetch next even subtile
        COMPUTE(jp * 2 + 1, Bs1);
        __syncthreads();                       // Bs0 ready; Bs1 reads done
    }

    // ---- final: reduce nm across the 16 lanes of each quad; owner-lane pm ----
#pragma unroll
    for (int q = 0; q < 16; ++q) {
        float v = nm[q];
#pragma unroll
        for (int off = 1; off < 16; off <<= 1) v = fminf(v, __shfl_xor(v, off));
        if (l15 == 0) {
            int row = ib + wi * 64 + (q >> 2) * 16 + quad * 4 + (q & 3);
            float d2 = fmaxf(v + sq[row], 0.f);
            atomicMin(&negmin[row], __float_as_uint(d2));
        }
    }
    if ((l15 >> 2) == quad) {     // this lane owns the tile-diag elems
#pragma unroll
        for (int s = 0; s < 2; ++s) {
            int ti = wj * 2 + s;
            int row = ib + wi * 64 + ti * 16 + l15;
            float d2 = fmaxf(pm[s] + sq[row], 0.f);
            atomicMax(&posmax[row], __float_as_uint(d2));
        }
    }
}

// ---------------- kernel 2: final combine ---------------------------------------
__global__ void k_final(const unsigned* __restrict__ posmax, const unsigned* __restrict__ negmin,
                        const float* __restrict__ scalars, float* __restrict__ out) {
    float acc = 0.f;
    for (int i = threadIdx.x; i < N; i += 1024) {
        float hp = sqrtf(__uint_as_float(posmax[i]));
        float hn = sqrtf(__uint_as_float(negmin[i]));
        acc += fmaxf(hp - hn + MARGIN, 0.f);
    }
#pragma unroll
    for (int off = 32; off; off >>= 1) acc += __shfl_xor(acc, off);
    __shared__ float red[16];
    if ((threadIdx.x & 63) == 0) red[threadIdx.x >> 6] = acc;
    __syncthreads();
    if (threadIdx.x == 0) {
        float tsum = 0.f;
#pragma unroll
        for (int i = 0; i < 16; ++i) tsum += red[i];
        float ssum = 0.f;
        for (int i = 0; i < 64; ++i) ssum += scalars[1 + i];
        out[0] = ssum + tsum * (1.f / N);
    }
}

extern "C" void kernel_launch(void* const* d_in, const int* in_sizes, int n_in,
                              void* d_out, int out_size, void* d_ws, size_t ws_size,
                              hipStream_t stream) {
    const float* feat = (const float*)d_in[0];
    const float* gt   = (const float*)d_in[1];
    const float* s0   = (const float*)d_in[2];
    const float* s1   = (const float*)d_in[3];
    const float* s2   = (const float*)d_in[4];
    const float* e0   = (const float*)d_in[5];
    const float* e1   = (const float*)d_in[6];
    const float* l0   = (const float*)d_in[7];
    const float* l1   = (const float*)d_in[8];
    float* out = (float*)d_out;

    char* ws = (char*)d_ws;
    __hip_bfloat16* fb = (__hip_bfloat16*)ws;                       // 4 MB
    float*    sq      = (float*)(ws + (size_t)N * C * 2);
    unsigned* posmax  = (unsigned*)(ws + (size_t)N * C * 2 + N * 4);
    unsigned* negmin  = (unsigned*)(ws + (size_t)N * C * 2 + N * 8);
    float*    scalars = (float*)(ws + (size_t)N * C * 2 + N * 12);  // 65 floats

    k_prep_sq<<<N / 4 + 64, 256, 0, stream>>>(feat, fb, sq, posmax, negmin,
                                              s0, s1, s2, gt, e0, e1, l0, l1, scalars);
    k_trip<<<512, 256, 0, stream>>>(fb, sq, posmax, negmin);
    k_final<<<1, 1024, 0, stream>>>(posmax, negmin, scalars, out);
}